// Round 2
// baseline (411.560 us; speedup 1.0000x reference)
//
#include <hip/hip_runtime.h>

// FuzzySystemLayer via split-bf16 MFMA. B=262144, C=256, D=64, O=8 (fp32 in/out).
// GEMM1 (32x32x16_bf16, transposed): acc[c_row, b_col] = log2-domain exponent
//   e = (2*x.c - x^2 - c^2) * k,  k = log2(e)/(2 w^2)
//   K layout (13 blocks of 16): [A=ch' | A=cl' | A=ch'] x [B=xh | B=xh | B=xl]
//   (c' = 2k*c, split hi/lo) + 1 extra K-block carrying -k*x^2 - k*c^2 in split bf16.
// Cluster rows permuted by swap23 so exp2(acc) registers ARE GEMM2's B fragments.
// GEMM2: out2[o, b] = W'^T @ memb, with W' row 8 = ones -> out2[8][b] = sum(memb).
// No LDS anywhere.

#define NB 262144
#define NC 256
#define ND 64
#define NO 8

typedef __attribute__((ext_vector_type(8))) short short8;
typedef __attribute__((ext_vector_type(16))) float floatx16;

__device__ __host__ inline unsigned short f2bf(float f) {
    unsigned u = __builtin_bit_cast(unsigned, f);
    u = u + 0x7FFFu + ((u >> 16) & 1u);
    return (unsigned short)(u >> 16);
}
__device__ inline float bf2f(unsigned short s) {
    unsigned u = ((unsigned)s) << 16;
    return __builtin_bit_cast(float, u);
}

// ---------------- prep: build A fragments (centers) and W' fragments ----------------
// Afrag: [t=8][kappa=13][lane=64][8 bf16]  (8*13*64*8 shorts = 104 KB)
// Wfrag: [k2=16][lane=64][8 bf16]          (16 KB), offset 8*13*64*8 shorts
__global__ void fuzzy_prep(const float* __restrict__ centers,
                           const float* __restrict__ widths,
                           const float* __restrict__ W,
                           unsigned short* __restrict__ ws) {
    const int lane = threadIdx.x;  // 64
    const int col = lane & 31;
    const int h = lane >> 5;

    if (blockIdx.x < 8) {
        const int t = blockIdx.x;
        // cluster placed at GEMM1 row `col` of tile t: swap bits 2<->3
        const int c = 32 * t + ((col & 19) | ((col & 4) << 1) | ((col & 8) >> 1));
        const float* cr = centers + c * ND;
        float w = widths[c];
        float kk = 1.4426950408889634f / (2.0f * w * w);  // log2(e)/(2w^2)

        float csq = 0.0f;
        for (int d = 0; d < ND; ++d) csq = fmaf(cr[d], cr[d], csq);

        unsigned short* base = ws;
        for (int kd = 0; kd < 4; ++kd) {
            for (int j = 0; j < 8; ++j) {
                int dim = kd * 16 + h * 8 + j;
                float a = 2.0f * kk * cr[dim];
                unsigned short ah = f2bf(a);
                unsigned short al = f2bf(a - bf2f(ah));
                base[((t * 13 + kd) * 64 + lane) * 8 + j] = ah;      // pairs xh
                base[((t * 13 + kd + 4) * 64 + lane) * 8 + j] = al;  // pairs xh
                base[((t * 13 + kd + 8) * 64 + lane) * 8 + j] = ah;  // pairs xl
            }
        }
        // kappa = 12: affine correction  -k*xsq - k*csq
        unsigned short v[8] = {0, 0, 0, 0, 0, 0, 0, 0};
        if (h == 0) {
            float Bc = csq * kk;
            float kl = kk - bf2f(f2bf(kk));
            float Bl = Bc - bf2f(f2bf(Bc));
            v[0] = f2bf(-kk);  // * xsq_hi
            v[1] = f2bf(-kk);  // * xsq_lo
            v[2] = f2bf(-kl);  // * xsq_hi
            v[3] = f2bf(-Bc);  // * 1
            v[4] = f2bf(-Bl);  // * 1
        }
        for (int j = 0; j < 8; ++j)
            base[((t * 13 + 12) * 64 + lane) * 8 + j] = v[j];
    } else {
        // W' fragments: A[m=o][k=c] for GEMM2; o = col; row 8 = ones (normalizer)
        unsigned short* wbase = ws + 8 * 13 * 64 * 8;
        for (int k2 = 0; k2 < 16; ++k2) {
            for (int j = 0; j < 8; ++j) {
                int c = k2 * 16 + h * 8 + j;  // natural cluster order (perm self-inverts)
                float val = (col < NO) ? W[c * NO + col] : (col == 8 ? 1.0f : 0.0f);
                wbase[(k2 * 64 + lane) * 8 + j] = f2bf(val);
            }
        }
    }
}

// ---------------- main ----------------
__global__ __launch_bounds__(256) void fuzzy_main(const float* __restrict__ x,
                                                  const short8* __restrict__ afrag,
                                                  const short8* __restrict__ wfrag,
                                                  float* __restrict__ out) {
    const int tid = threadIdx.x;
    const int wave = tid >> 6;
    const int lane = tid & 63;
    const int col = lane & 31;
    const int h = lane >> 5;
    const int b = (blockIdx.x * 4 + wave) * 32 + col;

    // ---- load x row chunks; build xh/xl B-fragments and x^2 ----
    short8 xh[4], xl[4];
    float xsq = 0.0f;
    const float* xrow = x + (size_t)b * ND;
#pragma unroll
    for (int kd = 0; kd < 4; ++kd) {
        const float4* p = (const float4*)(xrow + kd * 16 + h * 8);
        float4 v0 = p[0], v1 = p[1];
        float v[8] = {v0.x, v0.y, v0.z, v0.w, v1.x, v1.y, v1.z, v1.w};
        short8 hi, lo;
#pragma unroll
        for (int j = 0; j < 8; ++j) {
            xsq = fmaf(v[j], v[j], xsq);
            unsigned short hb = f2bf(v[j]);
            hi[j] = (short)hb;
            lo[j] = (short)f2bf(v[j] - bf2f(hb));
        }
        xh[kd] = hi;
        xl[kd] = lo;
    }
    xsq += __shfl_xor(xsq, 32, 64);

    // kappa=12 B-fragment: [xsq_h, xsq_l, xsq_h, 1, 1, 0,0,0] on h==0 lanes
    short8 f12;
    {
        unsigned short sh = f2bf(xsq);
        unsigned short sl = f2bf(xsq - bf2f(sh));
#pragma unroll
        for (int j = 0; j < 8; ++j) f12[j] = 0;
        if (h == 0) {
            f12[0] = (short)sh;
            f12[1] = (short)sl;
            f12[2] = (short)sh;
            f12[3] = (short)0x3F80;  // 1.0 bf16
            f12[4] = (short)0x3F80;
        }
    }

    // ---- GEMM1: 8 cluster tiles x 13 K-blocks ----
    floatx16 acc[8];
#pragma unroll
    for (int t = 0; t < 8; ++t)
#pragma unroll
        for (int i = 0; i < 16; ++i) acc[t][i] = 0.0f;

    const short8* ap = afrag + lane;
#pragma unroll 2
    for (int t = 0; t < 8; ++t) {
#pragma unroll
        for (int k = 0; k < 13; ++k) {
            short8 a = ap[(t * 13 + k) * 64];
            short8 bb = (k < 4) ? xh[k] : (k < 8) ? xh[k - 4] : (k < 12) ? xl[k - 8] : f12;
            acc[t] = __builtin_amdgcn_mfma_f32_32x32x16_bf16(a, bb, acc[t], 0, 0, 0);
        }
    }

    // ---- epilogue: row max (per b), exp2, pack to GEMM2 B-fragments ----
    float M = -3.0e38f;
#pragma unroll
    for (int t = 0; t < 8; ++t)
#pragma unroll
        for (int i = 0; i < 16; ++i) M = fmaxf(M, acc[t][i]);
    M = fmaxf(M, __shfl_xor(M, 32, 64));

    short8 pf[16];
#pragma unroll
    for (int t = 0; t < 8; ++t) {
#pragma unroll
        for (int i = 0; i < 16; ++i) {
            float p = __builtin_amdgcn_exp2f(acc[t][i] - M);
            pf[2 * t + (i >> 3)][i & 7] = (short)f2bf(p);
        }
    }

    // ---- GEMM2: out2 = W'^T @ memb  (rows: o=0..7 outputs, o=8 normalizer) ----
    floatx16 acc2;
#pragma unroll
    for (int i = 0; i < 16; ++i) acc2[i] = 0.0f;
    const short8* wp = wfrag + lane;
#pragma unroll 4
    for (int k2 = 0; k2 < 16; ++k2)
        acc2 = __builtin_amdgcn_mfma_f32_32x32x16_bf16(wp[k2 * 64], pf[k2], acc2, 0, 0, 0);

    // S = out2[row 8] lives at h==0, reg 4; broadcast to h==1 partner
    float S = acc2[4];
    float Sp = __shfl_xor(S, 32, 64);
    if (h) S = Sp;
    float inv = 1.0f / S;

    float4 r;
    r.x = acc2[0] * inv;
    r.y = acc2[1] * inv;
    r.z = acc2[2] * inv;
    r.w = acc2[3] * inv;
    // h=0 lanes hold o=0..3, h=1 lanes hold o=4..7 of the same b
    ((float4*)(out + (size_t)b * NO))[h] = r;
}

extern "C" void kernel_launch(void* const* d_in, const int* in_sizes, int n_in,
                              void* d_out, int out_size, void* d_ws, size_t ws_size,
                              hipStream_t stream) {
    const float* x       = (const float*)d_in[0];  // [B, D]
    const float* centers = (const float*)d_in[1];  // [C, D]
    const float* widths  = (const float*)d_in[2];  // [C]
    const float* W       = (const float*)d_in[3];  // [C, O]
    float* out = (float*)d_out;
    unsigned short* ws = (unsigned short*)d_ws;    // 120 KB used

    fuzzy_prep<<<9, 64, 0, stream>>>(centers, widths, W, ws);

    const short8* afrag = (const short8*)ws;
    const short8* wfrag = (const short8*)(ws + 8 * 13 * 64 * 8);
    fuzzy_main<<<NB / 128, 256, 0, stream>>>(x, afrag, wfrag, out);
}

// Round 3
// 176.650 us; speedup vs baseline: 2.3298x; 2.3298x over previous
//
#include <hip/hip_runtime.h>

// FuzzySystemLayer via split-bf16 MFMA, streaming per-tile (no max-subtraction:
// sum-normalization cancels any common scale; exponents stay in fp32 normal range).
// B=262144, C=256, D=64, O=8 (fp32 in/out).
//
// GEMM1 (32x32x16_bf16, transposed): acc[c_row, b_col] = log2-domain exponent
//   e = (2*x.c - x^2 - c^2) * k,  k = log2(e)/(2 w^2)
//   K layout (13 blocks of 16): [A=ch' | A=cl' | A=ch'] x [B=xh | B=xh | B=xl]
//   (c' = 2k*c, split hi/lo) + 1 K-block carrying -k*x^2 - k*c^2 in split bf16.
// Cluster rows permuted by swap23 so exp2(acc) registers ARE GEMM2's B fragments.
// GEMM2: out2[o, b] = W'^T @ memb, W' row 8 = ones -> normalizer.
// CRITICAL (round-2 lesson): no local array may be indexed by a runtime loop var —
// partial-unroll pragmas on loops indexing acc[]/pf[] demoted them to scratch
// (663 MB spill writes). Here every array index is inside a fully-unrolled loop.

#define NB 262144
#define NC 256
#define ND 64
#define NO 8

typedef __attribute__((ext_vector_type(8))) short short8;
typedef __attribute__((ext_vector_type(16))) float floatx16;

__device__ __host__ inline unsigned short f2bf(float f) {
    unsigned u = __builtin_bit_cast(unsigned, f);
    u = u + 0x7FFFu + ((u >> 16) & 1u);
    return (unsigned short)(u >> 16);
}
__device__ inline float bf2f(unsigned short s) {
    unsigned u = ((unsigned)s) << 16;
    return __builtin_bit_cast(float, u);
}

// ---------------- prep: build A fragments (centers) and W' fragments ----------------
// Afrag: [t=8][kappa=13][lane=64][8 bf16]  (104 KB)
// Wfrag: [k2=16][lane=64][8 bf16]          (16 KB), after Afrag
__global__ void fuzzy_prep(const float* __restrict__ centers,
                           const float* __restrict__ widths,
                           const float* __restrict__ W,
                           unsigned short* __restrict__ ws) {
    const int lane = threadIdx.x;  // 64
    const int col = lane & 31;
    const int h = lane >> 5;

    if (blockIdx.x < 8) {
        const int t = blockIdx.x;
        // cluster placed at GEMM1 row `col` of tile t: swap bits 2<->3
        const int c = 32 * t + ((col & 19) | ((col & 4) << 1) | ((col & 8) >> 1));
        const float* cr = centers + c * ND;
        float w = widths[c];
        float kk = 1.4426950408889634f / (2.0f * w * w);  // log2(e)/(2w^2)

        float csq = 0.0f;
        for (int d = 0; d < ND; ++d) csq = fmaf(cr[d], cr[d], csq);

        unsigned short* base = ws;
        for (int kd = 0; kd < 4; ++kd) {
            for (int j = 0; j < 8; ++j) {
                int dim = kd * 16 + h * 8 + j;
                float a = 2.0f * kk * cr[dim];
                unsigned short ah = f2bf(a);
                unsigned short al = f2bf(a - bf2f(ah));
                base[((t * 13 + kd) * 64 + lane) * 8 + j] = ah;      // pairs xh
                base[((t * 13 + kd + 4) * 64 + lane) * 8 + j] = al;  // pairs xh
                base[((t * 13 + kd + 8) * 64 + lane) * 8 + j] = ah;  // pairs xl
            }
        }
        // kappa = 12: affine correction  -k*xsq - k*csq
        unsigned short v[8] = {0, 0, 0, 0, 0, 0, 0, 0};
        if (h == 0) {
            float Bc = csq * kk;
            float kl = kk - bf2f(f2bf(kk));
            float Bl = Bc - bf2f(f2bf(Bc));
            v[0] = f2bf(-kk);  // * xsq_hi
            v[1] = f2bf(-kk);  // * xsq_lo
            v[2] = f2bf(-kl);  // * xsq_hi
            v[3] = f2bf(-Bc);  // * 1
            v[4] = f2bf(-Bl);  // * 1
        }
        for (int j = 0; j < 8; ++j)
            base[((t * 13 + 12) * 64 + lane) * 8 + j] = v[j];
    } else {
        // W' fragments: A[m=o][k=c] for GEMM2; o = col; row 8 = ones (normalizer)
        unsigned short* wbase = ws + 8 * 13 * 64 * 8;
        for (int k2 = 0; k2 < 16; ++k2) {
            for (int j = 0; j < 8; ++j) {
                int c = k2 * 16 + h * 8 + j;  // natural order (perm self-inverts)
                float val = (col < NO) ? W[c * NO + col] : (col == 8 ? 1.0f : 0.0f);
                wbase[(k2 * 64 + lane) * 8 + j] = f2bf(val);
            }
        }
    }
}

// ---------------- main ----------------
__global__ __launch_bounds__(256) void fuzzy_main(const float* __restrict__ x,
                                                  const short8* __restrict__ afrag,
                                                  const short8* __restrict__ wfrag,
                                                  float* __restrict__ out) {
    const int tid = threadIdx.x;
    const int wave = tid >> 6;
    const int lane = tid & 63;
    const int col = lane & 31;
    const int h = lane >> 5;
    const int b = (blockIdx.x * 4 + wave) * 32 + col;

    // ---- load x row chunks; build xh/xl B-fragments and x^2 ----
    short8 xh[4], xl[4];
    float xsq = 0.0f;
    const float* xrow = x + (size_t)b * ND;
#pragma unroll
    for (int kd = 0; kd < 4; ++kd) {
        const float4* p = (const float4*)(xrow + kd * 16 + h * 8);
        float4 v0 = p[0], v1 = p[1];
        float v[8] = {v0.x, v0.y, v0.z, v0.w, v1.x, v1.y, v1.z, v1.w};
        short8 hi, lo;
#pragma unroll
        for (int j = 0; j < 8; ++j) {
            xsq = fmaf(v[j], v[j], xsq);
            unsigned short hb = f2bf(v[j]);
            hi[j] = (short)hb;
            // lo is a ~2^-8 correction term: truncation (RTZ) is plenty
            lo[j] = (short)(__builtin_bit_cast(unsigned, v[j] - bf2f(hb)) >> 16);
        }
        xh[kd] = hi;
        xl[kd] = lo;
    }
    xsq += __shfl_xor(xsq, 32, 64);

    // kappa=12 B-fragment: [xsq_h, xsq_l, xsq_h, 1, 1, 0,0,0] on h==0 lanes
    short8 f12;
    {
        unsigned short sh = f2bf(xsq);
        unsigned short sl = f2bf(xsq - bf2f(sh));
#pragma unroll
        for (int j = 0; j < 8; ++j) f12[j] = 0;
        if (h == 0) {
            f12[0] = (short)sh;
            f12[1] = (short)sl;
            f12[2] = (short)sh;
            f12[3] = (short)0x3F80;  // 1.0 bf16
            f12[4] = (short)0x3F80;
        }
    }

    // ---- streamed tiles: GEMM1 (13 MFMA) -> exp2 -> GEMM2 (2 MFMA) ----
    floatx16 acc2;
#pragma unroll
    for (int i = 0; i < 16; ++i) acc2[i] = 0.0f;

    const short8* ap = afrag + lane;
    const short8* wp = wfrag + lane;

#pragma unroll 2
    for (int t = 0; t < 8; ++t) {
        floatx16 acc;
#pragma unroll
        for (int i = 0; i < 16; ++i) acc[i] = 0.0f;
#pragma unroll
        for (int k = 0; k < 13; ++k) {  // k static after full unroll -> no stack
            short8 a = ap[(t * 13 + k) * 64];
            short8 bb = (k < 4) ? xh[k] : (k < 8) ? xh[k - 4] : (k < 12) ? xl[k - 8] : f12;
            acc = __builtin_amdgcn_mfma_f32_32x32x16_bf16(a, bb, acc, 0, 0, 0);
        }
        short8 pf0, pf1;
#pragma unroll
        for (int i = 0; i < 16; ++i) {
            float p = __builtin_amdgcn_exp2f(acc[i]);
            unsigned short r = f2bf(p);
            if (i < 8) pf0[i] = (short)r;
            else       pf1[i - 8] = (short)r;
        }
        acc2 = __builtin_amdgcn_mfma_f32_32x32x16_bf16(wp[(2 * t + 0) * 64], pf0, acc2, 0, 0, 0);
        acc2 = __builtin_amdgcn_mfma_f32_32x32x16_bf16(wp[(2 * t + 1) * 64], pf1, acc2, 0, 0, 0);
    }

    // S = out2[row 8] lives at h==0, reg 4; broadcast to h==1 partner
    float S = acc2[4];
    float Sp = __shfl_xor(S, 32, 64);
    if (h) S = Sp;
    float inv = 1.0f / S;

    float4 r;
    r.x = acc2[0] * inv;
    r.y = acc2[1] * inv;
    r.z = acc2[2] * inv;
    r.w = acc2[3] * inv;
    // h=0 lanes hold o=0..3, h=1 lanes hold o=4..7 of the same b
    ((float4*)(out + (size_t)b * NO))[h] = r;
}

extern "C" void kernel_launch(void* const* d_in, const int* in_sizes, int n_in,
                              void* d_out, int out_size, void* d_ws, size_t ws_size,
                              hipStream_t stream) {
    const float* x       = (const float*)d_in[0];  // [B, D]
    const float* centers = (const float*)d_in[1];  // [C, D]
    const float* widths  = (const float*)d_in[2];  // [C]
    const float* W       = (const float*)d_in[3];  // [C, O]
    float* out = (float*)d_out;
    unsigned short* ws = (unsigned short*)d_ws;    // 120 KB used

    fuzzy_prep<<<9, 64, 0, stream>>>(centers, widths, W, ws);

    const short8* afrag = (const short8*)ws;
    const short8* wfrag = (const short8*)(ws + 8 * 13 * 64 * 8);
    fuzzy_main<<<NB / 128, 256, 0, stream>>>(x, afrag, wfrag, out);
}

// Round 4
// 127.197 us; speedup vs baseline: 3.2356x; 1.3888x over previous
//
#include <hip/hip_runtime.h>

// FuzzySystemLayer via split-bf16 MFMA, streaming per-tile, 2 b-tiles/wave.
// B=262144, C=256, D=64, O=8 (fp32 in/out).
//
// GEMM1 (32x32x16_bf16, transposed): acc[c_row, b_col] = log2-domain exponent
//   e = (2*x.c - x^2 - c^2) * k,  k = log2(e)/(2 w^2)
//   13 K-blocks: [ah x xh (kd=0..3)] [al x xh] [ah x xl] [c12 x f12]
//   but only 9 unique A fragments per tile (ah reused for the xl group).
// Cluster rows permuted by swap23 so exp2(acc) registers ARE GEMM2's B fragments.
// GEMM2: out2[o, b] = W'^T @ memb, W' row 8 = ones -> normalizer.
// Round-2 lesson: no local array indexed by a runtime loop var (scratch demotion).
// Round-3 lesson: VGPR=60 left loads serialized; this version deliberately holds
// ~200 regs so a full tile's 9 fragment loads (x2 at unroll 2) are in flight.

#define NB 262144
#define NC 256
#define ND 64
#define NO 8

typedef __attribute__((ext_vector_type(8))) short short8;
typedef __attribute__((ext_vector_type(16))) float floatx16;

__device__ __host__ inline unsigned short f2bf(float f) {
    unsigned u = __builtin_bit_cast(unsigned, f);
    u = u + 0x7FFFu + ((u >> 16) & 1u);
    return (unsigned short)(u >> 16);
}
__device__ inline float bf2f(unsigned short s) {
    unsigned u = ((unsigned)s) << 16;
    return __builtin_bit_cast(float, u);
}

// ---------------- prep ----------------
// Afrag: [t=8][idx=9][lane=64][8 bf16]   (72 KB)   idx: 0-3 ah, 4-7 al, 8 c12
// Wfrag: [k2=16][lane=64][8 bf16]        (16 KB), after Afrag
__global__ void fuzzy_prep(const float* __restrict__ centers,
                           const float* __restrict__ widths,
                           const float* __restrict__ W,
                           unsigned short* __restrict__ ws) {
    const int lane = threadIdx.x;  // 64
    const int col = lane & 31;
    const int h = lane >> 5;

    if (blockIdx.x < 8) {
        const int t = blockIdx.x;
        // cluster at GEMM1 row `col` of tile t: swap bits 2<->3 (self-inverse)
        const int c = 32 * t + ((col & 19) | ((col & 4) << 1) | ((col & 8) >> 1));
        const float* cr = centers + c * ND;
        float w = widths[c];
        float kk = 1.4426950408889634f / (2.0f * w * w);  // log2(e)/(2w^2)

        // this lane's 32 dims: kd*16 + h*8 + j  (vector loads)
        float vv[4][8];
        float part = 0.0f;
#pragma unroll
        for (int kd = 0; kd < 4; ++kd) {
            const float4* p = (const float4*)(cr + kd * 16 + h * 8);
            float4 a0 = p[0], a1 = p[1];
            vv[kd][0] = a0.x; vv[kd][1] = a0.y; vv[kd][2] = a0.z; vv[kd][3] = a0.w;
            vv[kd][4] = a1.x; vv[kd][5] = a1.y; vv[kd][6] = a1.z; vv[kd][7] = a1.w;
#pragma unroll
            for (int j = 0; j < 8; ++j) part = fmaf(vv[kd][j], vv[kd][j], part);
        }
        float csq = part + __shfl_xor(part, 32, 64);

        unsigned short* base = ws;
#pragma unroll
        for (int kd = 0; kd < 4; ++kd) {
#pragma unroll
            for (int j = 0; j < 8; ++j) {
                float a = 2.0f * kk * vv[kd][j];
                unsigned short ah = f2bf(a);
                unsigned short al = f2bf(a - bf2f(ah));
                base[((t * 9 + kd) * 64 + lane) * 8 + j] = ah;
                base[((t * 9 + 4 + kd) * 64 + lane) * 8 + j] = al;
            }
        }
        // idx 8: affine correction  -k*xsq - k*csq  (nonzero only on h==0)
        unsigned short v[8] = {0, 0, 0, 0, 0, 0, 0, 0};
        if (h == 0) {
            float Bc = csq * kk;
            float kl = kk - bf2f(f2bf(kk));
            float Bl = Bc - bf2f(f2bf(Bc));
            v[0] = f2bf(-kk);  // * xsq_hi
            v[1] = f2bf(-kk);  // * xsq_lo
            v[2] = f2bf(-kl);  // * xsq_hi
            v[3] = f2bf(-Bc);  // * 1
            v[4] = f2bf(-Bl);  // * 1
        }
#pragma unroll
        for (int j = 0; j < 8; ++j)
            base[((t * 9 + 8) * 64 + lane) * 8 + j] = v[j];
    } else {
        // W' fragments: A[m=o][k=c]; o=col; row 8 = ones (normalizer).
        // 4 blocks x 4 k2 each.
        unsigned short* wbase = ws + 8 * 9 * 64 * 8;
        const int k2base = (blockIdx.x - 8) * 4;
#pragma unroll
        for (int kq = 0; kq < 4; ++kq) {
            int k2 = k2base + kq;
#pragma unroll
            for (int j = 0; j < 8; ++j) {
                int c = k2 * 16 + h * 8 + j;  // natural order (perm self-inverts)
                float val = (col < NO) ? W[c * NO + col] : (col == 8 ? 1.0f : 0.0f);
                wbase[(k2 * 64 + lane) * 8 + j] = f2bf(val);
            }
        }
    }
}

// ---------------- main ----------------
__global__ __launch_bounds__(256) void fuzzy_main(const float* __restrict__ x,
                                                  const short8* __restrict__ afrag,
                                                  const short8* __restrict__ wfrag,
                                                  float* __restrict__ out) {
    const int tid = threadIdx.x;
    const int wave = tid >> 6;
    const int lane = tid & 63;
    const int col = lane & 31;
    const int h = lane >> 5;
    const int bbase = (blockIdx.x * 4 + wave) * 64;  // 64 b-columns per wave

    // ---- load both x rows; build xh/xl fragments, xsq, f12 ----
    short8 xh[2][4], xl[2][4];
    short8 f12[2];
#pragma unroll
    for (int u = 0; u < 2; ++u) {
        const float* xrow = x + (size_t)(bbase + u * 32 + col) * ND;
        float part = 0.0f;
#pragma unroll
        for (int kd = 0; kd < 4; ++kd) {
            const float4* p = (const float4*)(xrow + kd * 16 + h * 8);
            float4 v0 = p[0], v1 = p[1];
            float v[8] = {v0.x, v0.y, v0.z, v0.w, v1.x, v1.y, v1.z, v1.w};
            short8 hi, lo;
#pragma unroll
            for (int j = 0; j < 8; ++j) {
                part = fmaf(v[j], v[j], part);
                unsigned short hb = f2bf(v[j]);
                hi[j] = (short)hb;
                lo[j] = (short)(__builtin_bit_cast(unsigned, v[j] - bf2f(hb)) >> 16);
            }
            xh[u][kd] = hi;
            xl[u][kd] = lo;
        }
        float xsq = part + __shfl_xor(part, 32, 64);
        unsigned short sh = f2bf(xsq);
        unsigned short sl = f2bf(xsq - bf2f(sh));
        short8 f;
#pragma unroll
        for (int j = 0; j < 8; ++j) f[j] = 0;
        if (h == 0) {
            f[0] = (short)sh;
            f[1] = (short)sl;
            f[2] = (short)sh;
            f[3] = (short)0x3F80;  // 1.0 bf16
            f[4] = (short)0x3F80;
        }
        f12[u] = f;
    }

    floatx16 acc2[2];
#pragma unroll
    for (int u = 0; u < 2; ++u)
#pragma unroll
        for (int i = 0; i < 16; ++i) acc2[u][i] = 0.0f;

    const short8* ap = afrag + lane;
    const short8* wp = wfrag + lane;

#pragma unroll 2
    for (int t = 0; t < 8; ++t) {
        // 9 unique A fragments + 2 W fragments for this tile (explicit vars)
        short8 A0 = ap[(t * 9 + 0) * 64];
        short8 A1 = ap[(t * 9 + 1) * 64];
        short8 A2 = ap[(t * 9 + 2) * 64];
        short8 A3 = ap[(t * 9 + 3) * 64];
        short8 L0 = ap[(t * 9 + 4) * 64];
        short8 L1 = ap[(t * 9 + 5) * 64];
        short8 L2 = ap[(t * 9 + 6) * 64];
        short8 L3 = ap[(t * 9 + 7) * 64];
        short8 C12 = ap[(t * 9 + 8) * 64];
        short8 w0 = wp[(2 * t + 0) * 64];
        short8 w1 = wp[(2 * t + 1) * 64];

#pragma unroll
        for (int u = 0; u < 2; ++u) {
            floatx16 acc;
#pragma unroll
            for (int i = 0; i < 16; ++i) acc[i] = 0.0f;
            acc = __builtin_amdgcn_mfma_f32_32x32x16_bf16(A0, xh[u][0], acc, 0, 0, 0);
            acc = __builtin_amdgcn_mfma_f32_32x32x16_bf16(A1, xh[u][1], acc, 0, 0, 0);
            acc = __builtin_amdgcn_mfma_f32_32x32x16_bf16(A2, xh[u][2], acc, 0, 0, 0);
            acc = __builtin_amdgcn_mfma_f32_32x32x16_bf16(A3, xh[u][3], acc, 0, 0, 0);
            acc = __builtin_amdgcn_mfma_f32_32x32x16_bf16(L0, xh[u][0], acc, 0, 0, 0);
            acc = __builtin_amdgcn_mfma_f32_32x32x16_bf16(L1, xh[u][1], acc, 0, 0, 0);
            acc = __builtin_amdgcn_mfma_f32_32x32x16_bf16(L2, xh[u][2], acc, 0, 0, 0);
            acc = __builtin_amdgcn_mfma_f32_32x32x16_bf16(L3, xh[u][3], acc, 0, 0, 0);
            acc = __builtin_amdgcn_mfma_f32_32x32x16_bf16(A0, xl[u][0], acc, 0, 0, 0);
            acc = __builtin_amdgcn_mfma_f32_32x32x16_bf16(A1, xl[u][1], acc, 0, 0, 0);
            acc = __builtin_amdgcn_mfma_f32_32x32x16_bf16(A2, xl[u][2], acc, 0, 0, 0);
            acc = __builtin_amdgcn_mfma_f32_32x32x16_bf16(A3, xl[u][3], acc, 0, 0, 0);
            acc = __builtin_amdgcn_mfma_f32_32x32x16_bf16(C12, f12[u], acc, 0, 0, 0);

            short8 pf0, pf1;
#pragma unroll
            for (int i = 0; i < 16; ++i) {
                float p = __builtin_amdgcn_exp2f(acc[i]);
                unsigned short r = f2bf(p);
                if (i < 8) pf0[i] = (short)r;
                else       pf1[i - 8] = (short)r;
            }
            acc2[u] = __builtin_amdgcn_mfma_f32_32x32x16_bf16(w0, pf0, acc2[u], 0, 0, 0);
            acc2[u] = __builtin_amdgcn_mfma_f32_32x32x16_bf16(w1, pf1, acc2[u], 0, 0, 0);
        }
    }

    // ---- epilogue per b-tile ----
#pragma unroll
    for (int u = 0; u < 2; ++u) {
        float S = acc2[u][4];  // row 8 (normalizer) lives at h==0, reg 4
        float Sp = __shfl_xor(S, 32, 64);
        if (h) S = Sp;
        float inv = 1.0f / S;
        float4 r;
        r.x = acc2[u][0] * inv;
        r.y = acc2[u][1] * inv;
        r.z = acc2[u][2] * inv;
        r.w = acc2[u][3] * inv;
        // h=0 lanes hold o=0..3, h=1 lanes hold o=4..7 of the same b
        ((float4*)(out + (size_t)(bbase + u * 32 + col) * NO))[h] = r;
    }
}

extern "C" void kernel_launch(void* const* d_in, const int* in_sizes, int n_in,
                              void* d_out, int out_size, void* d_ws, size_t ws_size,
                              hipStream_t stream) {
    const float* x       = (const float*)d_in[0];  // [B, D]
    const float* centers = (const float*)d_in[1];  // [C, D]
    const float* widths  = (const float*)d_in[2];  // [C]
    const float* W       = (const float*)d_in[3];  // [C, O]
    float* out = (float*)d_out;
    unsigned short* ws = (unsigned short*)d_ws;    // 90 KB used

    fuzzy_prep<<<12, 64, 0, stream>>>(centers, widths, W, ws);

    const short8* afrag = (const short8*)ws;
    const short8* wfrag = (const short8*)(ws + 8 * 9 * 64 * 8);
    // 4096 waves: each handles 64 b-columns (2 tiles of 32)
    fuzzy_main<<<NB / 256, 256, 0, stream>>>(x, afrag, wfrag, out);
}

// Round 5
// 111.572 us; speedup vs baseline: 3.6887x; 1.1401x over previous
//
#include <hip/hip_runtime.h>

// FuzzySystemLayer: B=262144, C=256, D=64, O=8 (fp32 in/out).
// GEMM1 in fp16 (single product, 32x32x16_f16): acc[c_row, b_col] = log2 exponent
//   e = (2*x.c)*k - k*x^2 - k*c^2,  k = log2(e)/(2 w^2)
//   5 K-blocks: 4x [A=fp16(2k*c)] x [B=fp16(x)] + 1 affine block with internal
//   hi/lo fp16 splits of k, x^2, k*c^2 (pair error ~2^-22).
// GEMM2 in bf16 (memb spans 2^-40..2^-200; fp16 would flush to 0 -> NaN).
//   out2[o, b] = W'^T @ memb, W' row 8 = ones -> normalizer.
// Fragments (56 KB) staged to LDS once per 512-thread block (2 blocks/CU).
// exp2 -> bf16 via v_perm (RTZ): normalization cancels the dominant cluster's
// truncation; residual error ~2e-4.
// Round-2 lesson: no local array indexed by a runtime var (scratch demotion).
// Round-4 lesson: per-wave L2 fragment loads (369 MB at ~250 cyc) were the
// latency wall; LDS staging + 2.6x fewer MFMA/VALU ops attack exactly that.

#define NB 262144
#define NC 256
#define ND 64
#define NO 8

typedef __attribute__((ext_vector_type(8))) short short8;
typedef __attribute__((ext_vector_type(8))) _Float16 half8;
typedef __attribute__((ext_vector_type(16))) float floatx16;

// ws layout in shorts:
//   A (fp16):  ((t*5 + idx)*64 + lane)*8 + j   idx 0..3 = 2k*c, idx 4 = affine
//   W (bf16):  20480 + (k2*64 + lane)*8 + j    k2 = 0..15
// total 28672 shorts = 56 KB
#define WOFF 20480
#define WS_SHORTS 28672
#define WS_UINT4 3584

__device__ __host__ inline unsigned short f2bf(float f) {
    unsigned u = __builtin_bit_cast(unsigned, f);
    u = u + 0x7FFFu + ((u >> 16) & 1u);
    return (unsigned short)(u >> 16);
}
__device__ inline unsigned short f2h(float f) {
    return __builtin_bit_cast(unsigned short, (_Float16)f);
}

// ---------------- prep ----------------
__global__ void fuzzy_prep(const float* __restrict__ centers,
                           const float* __restrict__ widths,
                           const float* __restrict__ W,
                           unsigned short* __restrict__ ws) {
    const int lane = threadIdx.x;  // 64
    const int col = lane & 31;
    const int h = lane >> 5;

    if (blockIdx.x < 8) {
        const int t = blockIdx.x;
        // cluster at GEMM1 row `col` of tile t: swap bits 2<->3 (self-inverse)
        const int c = 32 * t + ((col & 19) | ((col & 4) << 1) | ((col & 8) >> 1));
        const float* cr = centers + c * ND;
        float w = widths[c];
        float kk = 1.4426950408889634f / (2.0f * w * w);  // log2(e)/(2w^2)

        float vv[4][8];
        float part = 0.0f;
#pragma unroll
        for (int kd = 0; kd < 4; ++kd) {
            const float4* p = (const float4*)(cr + kd * 16 + h * 8);
            float4 a0 = p[0], a1 = p[1];
            vv[kd][0] = a0.x; vv[kd][1] = a0.y; vv[kd][2] = a0.z; vv[kd][3] = a0.w;
            vv[kd][4] = a1.x; vv[kd][5] = a1.y; vv[kd][6] = a1.z; vv[kd][7] = a1.w;
#pragma unroll
            for (int j = 0; j < 8; ++j) part = fmaf(vv[kd][j], vv[kd][j], part);
        }
        float csq = part + __shfl_xor(part, 32, 64);

#pragma unroll
        for (int kd = 0; kd < 4; ++kd)
#pragma unroll
            for (int j = 0; j < 8; ++j)
                ws[((t * 5 + kd) * 64 + lane) * 8 + j] = f2h(2.0f * kk * vv[kd][j]);

        // affine block (idx 4), nonzero only on h==0:
        // A = [-k_h, -k_h, -k_l, -(k*c^2)_h, -(k*c^2)_l, 0,0,0]
        // pairs B = [x2_h, x2_l, x2_h, 1, 1, 0,0,0]
        unsigned short v[8] = {0, 0, 0, 0, 0, 0, 0, 0};
        if (h == 0) {
            float kh = (float)(_Float16)kk;
            float kl = kk - kh;
            float Bc = csq * kk;
            float Bh = (float)(_Float16)Bc;
            float Bl = Bc - Bh;
            v[0] = f2h(-kh);
            v[1] = f2h(-kh);
            v[2] = f2h(-kl);
            v[3] = f2h(-Bh);
            v[4] = f2h(-Bl);
        }
#pragma unroll
        for (int j = 0; j < 8; ++j)
            ws[((t * 5 + 4) * 64 + lane) * 8 + j] = v[j];
    } else {
        // W' fragments (bf16): A[m=o][k=c]; o=col; row 8 = ones (normalizer)
        const int k2base = (blockIdx.x - 8) * 4;
#pragma unroll
        for (int kq = 0; kq < 4; ++kq) {
            int k2 = k2base + kq;
#pragma unroll
            for (int j = 0; j < 8; ++j) {
                int c = k2 * 16 + h * 8 + j;  // natural order (perm self-inverts)
                float val = (col < NO) ? W[c * NO + col] : (col == 8 ? 1.0f : 0.0f);
                ws[WOFF + (k2 * 64 + lane) * 8 + j] = f2bf(val);
            }
        }
    }
}

// ---------------- main ----------------
__global__ __launch_bounds__(512, 4) void fuzzy_main(
    const float* __restrict__ x,
    const uint4* __restrict__ ws4,
    float* __restrict__ out) {
    __shared__ short lds_s[WS_SHORTS];

    const int tid = threadIdx.x;
    const int wave = tid >> 6;
    const int lane = tid & 63;
    const int col = lane & 31;
    const int h = lane >> 5;
    const int bbase = (blockIdx.x * 8 + wave) * 64;  // 64 b-columns per wave

    // ---- stage fragments to LDS (56 KB, 7 x 512 x 16B) ----
    {
        uint4* l4 = (uint4*)lds_s;
#pragma unroll
        for (int i = 0; i < 7; ++i) l4[tid + i * 512] = ws4[tid + i * 512];
    }

    // ---- load both x rows; build fp16 xh fragments, xsq, f12 ----
    half8 xh[2][4];
    half8 f12[2];
#pragma unroll
    for (int u = 0; u < 2; ++u) {
        const float* xrow = x + (size_t)(bbase + u * 32 + col) * ND;
        float part = 0.0f;
#pragma unroll
        for (int kd = 0; kd < 4; ++kd) {
            const float4* p = (const float4*)(xrow + kd * 16 + h * 8);
            float4 v0 = p[0], v1 = p[1];
            float v[8] = {v0.x, v0.y, v0.z, v0.w, v1.x, v1.y, v1.z, v1.w};
            half8 hh;
#pragma unroll
            for (int j = 0; j < 8; ++j) {
                part = fmaf(v[j], v[j], part);
                hh[j] = (_Float16)v[j];
            }
            xh[u][kd] = hh;
        }
        float xsq = part + __shfl_xor(part, 32, 64);
        float sh = (float)(_Float16)xsq;
        float sl = xsq - sh;
        half8 f;
#pragma unroll
        for (int j = 0; j < 8; ++j) f[j] = (_Float16)0.0f;
        if (h == 0) {
            f[0] = (_Float16)sh;
            f[1] = (_Float16)sl;
            f[2] = (_Float16)sh;
            f[3] = (_Float16)1.0f;
            f[4] = (_Float16)1.0f;
        }
        f12[u] = f;
    }

    __syncthreads();

    floatx16 acc2[2];
#pragma unroll
    for (int u = 0; u < 2; ++u)
#pragma unroll
        for (int i = 0; i < 16; ++i) acc2[u][i] = 0.0f;

#pragma unroll 2
    for (int t = 0; t < 8; ++t) {
        const half8 A0 = *(const half8*)&lds_s[((t * 5 + 0) * 64 + lane) * 8];
        const half8 A1 = *(const half8*)&lds_s[((t * 5 + 1) * 64 + lane) * 8];
        const half8 A2 = *(const half8*)&lds_s[((t * 5 + 2) * 64 + lane) * 8];
        const half8 A3 = *(const half8*)&lds_s[((t * 5 + 3) * 64 + lane) * 8];
        const half8 C12 = *(const half8*)&lds_s[((t * 5 + 4) * 64 + lane) * 8];
        const short8 w0 = *(const short8*)&lds_s[WOFF + ((2 * t + 0) * 64 + lane) * 8];
        const short8 w1 = *(const short8*)&lds_s[WOFF + ((2 * t + 1) * 64 + lane) * 8];

#pragma unroll
        for (int u = 0; u < 2; ++u) {
            floatx16 acc;
#pragma unroll
            for (int i = 0; i < 16; ++i) acc[i] = 0.0f;
            acc = __builtin_amdgcn_mfma_f32_32x32x16_f16(A0, xh[u][0], acc, 0, 0, 0);
            acc = __builtin_amdgcn_mfma_f32_32x32x16_f16(A1, xh[u][1], acc, 0, 0, 0);
            acc = __builtin_amdgcn_mfma_f32_32x32x16_f16(A2, xh[u][2], acc, 0, 0, 0);
            acc = __builtin_amdgcn_mfma_f32_32x32x16_f16(A3, xh[u][3], acc, 0, 0, 0);
            acc = __builtin_amdgcn_mfma_f32_32x32x16_f16(C12, f12[u], acc, 0, 0, 0);

            // exp2 -> bf16 (RTZ) two-at-a-time via v_perm
            unsigned p0 = __builtin_bit_cast(unsigned, __builtin_amdgcn_exp2f(acc[0]));
            unsigned p1 = __builtin_bit_cast(unsigned, __builtin_amdgcn_exp2f(acc[1]));
            unsigned p2 = __builtin_bit_cast(unsigned, __builtin_amdgcn_exp2f(acc[2]));
            unsigned p3 = __builtin_bit_cast(unsigned, __builtin_amdgcn_exp2f(acc[3]));
            unsigned p4 = __builtin_bit_cast(unsigned, __builtin_amdgcn_exp2f(acc[4]));
            unsigned p5 = __builtin_bit_cast(unsigned, __builtin_amdgcn_exp2f(acc[5]));
            unsigned p6 = __builtin_bit_cast(unsigned, __builtin_amdgcn_exp2f(acc[6]));
            unsigned p7 = __builtin_bit_cast(unsigned, __builtin_amdgcn_exp2f(acc[7]));
            unsigned p8 = __builtin_bit_cast(unsigned, __builtin_amdgcn_exp2f(acc[8]));
            unsigned p9 = __builtin_bit_cast(unsigned, __builtin_amdgcn_exp2f(acc[9]));
            unsigned pa = __builtin_bit_cast(unsigned, __builtin_amdgcn_exp2f(acc[10]));
            unsigned pb = __builtin_bit_cast(unsigned, __builtin_amdgcn_exp2f(acc[11]));
            unsigned pc = __builtin_bit_cast(unsigned, __builtin_amdgcn_exp2f(acc[12]));
            unsigned pd = __builtin_bit_cast(unsigned, __builtin_amdgcn_exp2f(acc[13]));
            unsigned pe = __builtin_bit_cast(unsigned, __builtin_amdgcn_exp2f(acc[14]));
            unsigned pf = __builtin_bit_cast(unsigned, __builtin_amdgcn_exp2f(acc[15]));
            uint4 q0, q1;
            q0.x = __builtin_amdgcn_perm(p1, p0, 0x07060302u);
            q0.y = __builtin_amdgcn_perm(p3, p2, 0x07060302u);
            q0.z = __builtin_amdgcn_perm(p5, p4, 0x07060302u);
            q0.w = __builtin_amdgcn_perm(p7, p6, 0x07060302u);
            q1.x = __builtin_amdgcn_perm(p9, p8, 0x07060302u);
            q1.y = __builtin_amdgcn_perm(pb, pa, 0x07060302u);
            q1.z = __builtin_amdgcn_perm(pd, pc, 0x07060302u);
            q1.w = __builtin_amdgcn_perm(pf, pe, 0x07060302u);
            short8 pf0 = __builtin_bit_cast(short8, q0);
            short8 pf1 = __builtin_bit_cast(short8, q1);

            acc2[u] = __builtin_amdgcn_mfma_f32_32x32x16_bf16(w0, pf0, acc2[u], 0, 0, 0);
            acc2[u] = __builtin_amdgcn_mfma_f32_32x32x16_bf16(w1, pf1, acc2[u], 0, 0, 0);
        }
    }

    // ---- epilogue per b-tile ----
#pragma unroll
    for (int u = 0; u < 2; ++u) {
        float S = acc2[u][4];  // row 8 (normalizer) lives at h==0, reg 4
        float Sp = __shfl_xor(S, 32, 64);
        if (h) S = Sp;
        float inv = 1.0f / S;
        float4 r;
        r.x = acc2[u][0] * inv;
        r.y = acc2[u][1] * inv;
        r.z = acc2[u][2] * inv;
        r.w = acc2[u][3] * inv;
        // h=0 lanes hold o=0..3, h=1 lanes hold o=4..7 of the same b
        ((float4*)(out + (size_t)(bbase + u * 32 + col) * NO))[h] = r;
    }
}

extern "C" void kernel_launch(void* const* d_in, const int* in_sizes, int n_in,
                              void* d_out, int out_size, void* d_ws, size_t ws_size,
                              hipStream_t stream) {
    const float* x       = (const float*)d_in[0];  // [B, D]
    const float* centers = (const float*)d_in[1];  // [C, D]
    const float* widths  = (const float*)d_in[2];  // [C]
    const float* W       = (const float*)d_in[3];  // [C, O]
    float* out = (float*)d_out;
    unsigned short* ws = (unsigned short*)d_ws;    // 56 KB used

    fuzzy_prep<<<12, 64, 0, stream>>>(centers, widths, W, ws);
    // 512 blocks x 512 threads; each wave handles 64 b-columns
    fuzzy_main<<<NB / 512, 512, 0, stream>>>(x, (const uint4*)ws, out);
}